// Round 18
// baseline (142.329 us; speedup 1.0000x reference)
//
#include <hip/hip_runtime.h>
#include <hip/hip_bf16.h>
#include <stdint.h>

// MHA: out = softmax_mask((X Wq)(X Wk)^T / sqrt(dh)) (X Wv), per-head, per-query valid_len mask.
// B=8 S=1024 D=1024 H=16 DH=64. f32 in/out, bf16 MFMA internally.
// R18: GEMM is LDS-pipe-bound (derived: 16 waves x (8A + 4Bx2.9) b128 x 12cyc matches 85us).
//      Fix the B-read 8-way conflict WITHOUT touching the global layout (R9/R14 source
//      permutations broke coalescing): reg-stage B (2 named u16x8 scalars — no arrays/lambdas,
//      the R12/13 spill trigger) -> ds_write to XOR-swizzled LDS (chunk ^ ((row>>1)&3), the
//      map R12 measured conflicts=0 with). A stays DMA. Write-late (T14). Rest = R17.

#define B_  8
#define S_  1024
#define D_  1024
#define H_  16
#define DH_ 64

typedef short bf16x8 __attribute__((ext_vector_type(8)));
typedef float f32x4  __attribute__((ext_vector_type(4)));
typedef unsigned short u16;
typedef uint32_t u32;
typedef u16 u16x8 __attribute__((ext_vector_type(8)));
typedef u16 u16x4 __attribute__((ext_vector_type(4)));

#define MASKVAL  (-1442.6950408889634f)            // -1000 * log2(e)
#define QSCALE   (0.18033688011112042f)            // (1/sqrt(64)) * log2(e)

union U4 { u32 u[4]; bf16x8 v; };

__device__ __forceinline__ u16 f2bf(float f) {
    union { float f; uint32_t u; } v; v.f = f;
    uint32_t u = v.u;
    return (u16)((u + 0x7FFFu + ((u >> 16) & 1u)) >> 16);   // RNE
}

__device__ __forceinline__ u32 cvtpk(float lo, float hi) {
    u32 r;
    asm("v_cvt_pk_bf16_f32 %0, %1, %2" : "=v"(r) : "v"(lo), "v"(hi));
    return r;
}

__device__ __forceinline__ void gload16(const void* g, const void* l) {
    __builtin_amdgcn_global_load_lds(
        (const __attribute__((address_space(1))) void*)g,
        (__attribute__((address_space(3))) void*)l, 16, 0, 0);
}

// xor-32 reductions via v_permlane32_swap (VALU pipe, not LDS).
__device__ __forceinline__ float xor32max(float v) {
    float a = v, b = v;
    asm volatile("" : "+v"(b));
    asm("v_permlane32_swap_b32 %0, %1" : "+v"(a), "+v"(b));
    return fmaxf(a, b);
}
__device__ __forceinline__ float xor32add(float v) {
    float a = v, b = v;
    asm volatile("" : "+v"(b));
    asm("v_permlane32_swap_b32 %0, %1" : "+v"(a), "+v"(b));
    return a + b;
}

// ---------------- W[k][n] f32 -> Wt[n][k] bf16 (linear layout), z selects {Wq,Wk,Wv} ----------------
__global__ void transpose_w3_kernel(const float* __restrict__ Wq, const float* __restrict__ Wk,
                                    const float* __restrict__ Wv, u16* __restrict__ Wts) {
    __shared__ u16 tile[32 * 33];
    const int z = blockIdx.z;
    const float* W = (z == 0) ? Wq : (z == 1) ? Wk : Wv;
    u16* Wt = Wts + (size_t)z * D_ * D_;
    int k0 = blockIdx.y * 32, n0 = blockIdx.x * 32;
    int t = threadIdx.x;
    int c = t & 31;
    for (int p = 0; p < 4; ++p) {
        int r = p * 8 + (t >> 5);
        tile[r * 33 + c] = f2bf(W[(size_t)(k0 + r) * D_ + n0 + c]);
    }
    __syncthreads();
    int rn = t >> 3, c4 = t & 7;
    u16x4 v;
    for (int j = 0; j < 4; ++j) v[j] = tile[(c4 * 4 + j) * 33 + rn];
    *(u16x4*)(Wt + (size_t)(n0 + rn) * D_ + k0 + c4 * 4) = v;
}

// ---------------- per-batch bitonic sort of q-rows by valid_len (0 -> S, sorted last) ----------------
__global__ __launch_bounds__(1024) void sort_vlen_kernel(const int* __restrict__ vlen,
                                                         int* __restrict__ qidx) {
    __shared__ u32 sk[1024];
    const int b = blockIdx.x, t = threadIdx.x;
    int k = vlen[b * S_ + t];
    u32 key = (k == 0) ? (u32)S_ : (u32)k;
    sk[t] = (key << 10) | (u32)t;
    __syncthreads();
    for (int sz = 2; sz <= 1024; sz <<= 1) {
        for (int st = sz >> 1; st > 0; st >>= 1) {
            int j = t ^ st;
            if (j > t) {
                u32 a = sk[t], c = sk[j];
                bool des = (t & sz) != 0;
                if ((a > c) != des) { sk[t] = c; sk[j] = a; }
            }
            __syncthreads();
        }
    }
    qidx[b * S_ + t] = (int)(sk[t] & 1023u);
}

// ---------------- fused QKV GEMM, BN=256 at 8 waves; B reg-staged to swizzled LDS ----------------
// grid (64, 12); y -> (z = y>>2, n0 = (y&3)*256). 128(M)x256(N) tile, BK=32, 512 threads.
// Wave grid 2x4: wr = w>>2 (M), wc = w&3 (N); each wave 64x64, acc[4][4].
// A staged raw f32 via gload_lds (source-swizzled chunks, 2-way free). B: linear coalesced
// global_load -> 2 named u16x8 regs -> ds_write_b128 at chunk x^((row>>1)&3) (conflict-free
// b128 reads: slots (4r + l4^((r>>1)&3)) mod 8 cover all 8 exactly 2x).
// z<2: C[m][n] bf16 (qb/kb). z==2: LDS-transpose tile -> vt (R17 fusion).
__global__ __launch_bounds__(512, 4) void gemm_qkv_kernel(const float* __restrict__ Aq,
                                                          const float* __restrict__ Ak,
                                                          const float* __restrict__ Av,
                                                          const u16* __restrict__ wts,
                                                          u16* __restrict__ qb, u16* __restrict__ kb,
                                                          u16* __restrict__ vt) {
    __shared__ __align__(16) char smem_g[65536];
    float* lds_a = (float*)smem_g;            // [2][128*32] f32 = 2 x 16 KB
    u16*  lds_b = (u16*)(smem_g + 32768);     // [2][256*32] u16 = 2 x 16 KB (swizzled chunks)
    const int zy = blockIdx.y;
    const int z = zy >> 2;
    const float* A = (z == 0) ? Aq : (z == 1) ? Ak : Av;
    const u16* Bt = wts + (size_t)z * D_ * D_;
    u16* C = (z == 0) ? qb : (z == 1) ? kb : vt;
    const float cmul = (z == 0) ? QSCALE : 1.0f;

    const int t = threadIdx.x, w = t >> 6, l = t & 63;
    const int m0 = blockIdx.x * 128, n0 = (zy & 3) * 256;
    const int wr = w >> 2, wc = w & 3;
    const int l15 = l & 15, l4 = l >> 4;
    f32x4 acc[4][4] = {};

    // A staging (DMA, unchanged from R17)
    auto stageA = [&](int buf, int kt) {
        int k0 = kt * 32;
        #pragma unroll
        for (int i = 0; i < 2; ++i) {
            int c = i * 512 + t;
            int row = c >> 3, xs = (c & 7) ^ (row & 7);
            gload16(A + (size_t)(m0 + row) * D_ + k0 + xs * 4, &lds_a[buf * 4096 + c * 4]);
        }
    };

    // B staging addresses (loop-invariant): thread t -> rows br0, br0+128; logical chunk bx
    const int br0 = t >> 2, bx = t & 3;
    const u16* bgp0 = Bt + (size_t)(n0 + br0) * D_ + bx * 8;          // + kt*32
    const u16* bgp1 = bgp0 + (size_t)128 * D_;
    const int bdst0 = (br0 * 4 + (bx ^ ((br0 >> 1) & 3))) * 8;        // swizzled LDS chunk
    const int bdst1 = bdst0 + 4096;                                    // row+128: same XOR

    // prologue: A buf0 (DMA) + B buf0 (reg->swizzled ds_write)
    stageA(0, 0);
    {
        u16x8 p0 = *(const u16x8*)(bgp0);
        u16x8 p1 = *(const u16x8*)(bgp1);
        *(u16x8*)&lds_b[bdst0] = p0;
        *(u16x8*)&lds_b[bdst1] = p1;
    }
    __syncthreads();

    int buf = 0;
    for (int kt = 0; kt < 32; ++kt) {
        u16x8 nb0, nb1;
        if (kt + 1 < 32) {
            stageA(buf ^ 1, kt + 1);
            nb0 = *(const u16x8*)(bgp0 + (kt + 1) * 32);
            nb1 = *(const u16x8*)(bgp1 + (kt + 1) * 32);
        }
        bf16x8 af[4], bfr[4];
        #pragma unroll
        for (int mi = 0; mi < 4; ++mi) {
            int r = wr * 64 + mi * 16 + l15;
            int c0 = (l4 * 2) ^ (r & 7), c1 = (l4 * 2 + 1) ^ (r & 7);
            float4 fa0 = *(const float4*)&lds_a[buf * 4096 + r * 32 + c0 * 4];
            float4 fa1 = *(const float4*)&lds_a[buf * 4096 + r * 32 + c1 * 4];
            U4 d;
            d.u[0] = cvtpk(fa0.x, fa0.y); d.u[1] = cvtpk(fa0.z, fa0.w);
            d.u[2] = cvtpk(fa1.x, fa1.y); d.u[3] = cvtpk(fa1.z, fa1.w);
            af[mi] = d.v;
        }
        #pragma unroll
        for (int ni = 0; ni < 4; ++ni) {
            int r = wc * 64 + ni * 16 + l15;
            bfr[ni] = *(const bf16x8*)&lds_b[buf * 8192 + (r * 4 + (l4 ^ ((r >> 1) & 3))) * 8];
        }
        #pragma unroll
        for (int mi = 0; mi < 4; ++mi)
            #pragma unroll
            for (int ni = 0; ni < 4; ++ni)
                acc[mi][ni] = __builtin_amdgcn_mfma_f32_16x16x32_bf16(af[mi], bfr[ni], acc[mi][ni], 0, 0, 0);
        if (kt + 1 < 32) {                 // write-late (T14): HBM latency hidden under MFMA
            *(u16x8*)&lds_b[(buf ^ 1) * 8192 + bdst0] = nb0;
            *(u16x8*)&lds_b[(buf ^ 1) * 8192 + bdst1] = nb1;
        }
        __syncthreads();
        buf ^= 1;
    }

    if (z == 2) {
        // V: LDS-transpose tile -> vt. T[256 n][128 m] u16, m-chunk XOR-swizzled by (n&7).
        u16* T = (u16*)smem_g;   // 64 KB exactly
        #pragma unroll
        for (int mi = 0; mi < 4; ++mi)
            #pragma unroll
            for (int ni = 0; ni < 4; ++ni)
                #pragma unroll
                for (int r = 0; r < 4; ++r) {
                    int nl = wc * 64 + ni * 16 + l15;
                    int ml = wr * 64 + mi * 16 + l4 * 4 + r;
                    T[nl * 128 + (ml ^ ((nl & 7) << 3))] = f2bf(acc[mi][ni][r] * cmul);
                }
        __syncthreads();
        const int nr = t >> 1, hf = t & 1;
        const size_t vbase = ((size_t)((m0 >> 10) * 1024 + n0 + nr)) * 1024 + (m0 & 1023) + hf * 64;
        #pragma unroll
        for (int c = 0; c < 8; ++c) {
            int cm = hf * 8 + c;
            u16x8 vv = *(u16x8*)&T[nr * 128 + ((cm ^ (nr & 7)) * 8)];
            *(u16x8*)&C[vbase + c * 8] = vv;
        }
    } else {
        // epilogue: C/D layout col=lane&15, row=(lane>>4)*4+reg (m89-verified)
        #pragma unroll
        for (int mi = 0; mi < 4; ++mi)
            #pragma unroll
            for (int ni = 0; ni < 4; ++ni)
                #pragma unroll
                for (int r = 0; r < 4; ++r) {
                    int m = m0 + wr * 64 + mi * 16 + l4 * 4 + r;
                    int n = n0 + wc * 64 + ni * 16 + l15;
                    C[(size_t)m * D_ + n] = f2bf(acc[mi][ni][r] * cmul);
                }
    }
}

// ---------------- flash attention: 8 waves x 16q, MERGED paired q-jobs, XCD-locality (R10) ---------
// 512 blocks: n&7 = XCD slot; j = n>>3: bh = (n&7) + 8*(j>>2), pair p = j&3.
// ONE k-loop over nkt(qblk 7-p) tiles; each tile staged once and consumed by BOTH jobs
// (qblk 7-p and qblk p), each guarded by its per-wave nktw (skipped tiles contribute exactly 0).
__global__ __launch_bounds__(512) void attn_kernel(const u16* __restrict__ qb,
                                                   const u16* __restrict__ kb,
                                                   const u16* __restrict__ vt,
                                                   const int* __restrict__ vlen,
                                                   const int* __restrict__ qidx,
                                                   float* __restrict__ out) {
    __shared__ __align__(16) char smem_raw[34816];   // stage 2x(8K K + 8K Vt) = 32K; epilogue 34K
    auto kv = [&](int buf, int which) -> u16* {
        return (u16*)(smem_raw + buf * 16384 + which * 8192);
    };

    const int t = threadIdx.x, w = t >> 6, l = t & 63;
    const int n = blockIdx.x;
    const int x = n & 7, j = n >> 3;
    const int bh = x + 8 * (j >> 2);
    const int p = j & 3;
    const int b = bh >> 4, h = bh & 15;
    const int l15 = l & 15, l4 = l >> 4;
    const bool rowe = ((l & 16) == 0);

    const u16* kbase = kb + ((size_t)(b * S_)) * D_ + h * 64;
    const u16* vbase = vt + ((size_t)bh * 64) * (size_t)S_;

    // 512 threads: one 16B chunk of K and one of Vt each per tile (source-swizzled)
    const int kr_s = t >> 3, x_s = (t & 7) ^ (kr_s & 7);
    auto stage = [&](int buf, int kt) {
        gload16(kbase + (size_t)(kt * 64 + kr_s) * D_ + x_s * 8, &kv(buf, 0)[t * 8]);
        gload16(vbase + (size_t)kr_s * S_ + kt * 64 + x_s * 8, &kv(buf, 1)[t * 8]);
    };

    // P-redistribution: permlane32_swap + xor16 shuffle
    auto redist = [&](u32 P, u32 Q, u32& oe, u32& oo) {
        u32 X = P, Y = Q;
        asm("v_permlane32_swap_b32 %0, %1" : "+v"(X), "+v"(Y));
        u32 t1 = (u32)__shfl_xor((int)Y, 16, 64);
        u32 t2 = (u32)__shfl_xor((int)X, 16, 64);
        oe = rowe ? X : t1;
        oo = rowe ? t2 : Y;
    };

    auto wavemax = [&](int v) {
        int s1 = __shfl_xor(v, 1, 64);  v = v > s1 ? v : s1;
        int s2 = __shfl_xor(v, 2, 64);  v = v > s2 ? v : s2;
        int s4 = __shfl_xor(v, 4, 64);  v = v > s4 ? v : s4;
        int s8 = __shfl_xor(v, 8, 64);  v = v > s8 ? v : s8;
        return v;
    };

    const int q0a = (7 - p) * 128, q0b = p * 128;

    const int qia = qidx[b * S_ + q0a + w * 16 + l15];
    const u16* qpa = qb + ((size_t)(b * S_ + qia)) * D_ + h * 64 + l4 * 8;
    const bf16x8 bqa0 = *(const bf16x8*)qpa;
    const bf16x8 bqa1 = *(const bf16x8*)(qpa + 32);
    const int vla = vlen[b * S_ + qia];

    const int qib = qidx[b * S_ + q0b + w * 16 + l15];
    const u16* qpb = qb + ((size_t)(b * S_ + qib)) * D_ + h * 64 + l4 * 8;
    const bf16x8 bqb0 = *(const bf16x8*)qpb;
    const bf16x8 bqb1 = *(const bf16x8*)(qpb + 32);
    const int vlb = vlen[b * S_ + qib];

    int mk = vlen[b * S_ + qidx[b * S_ + q0a + 127]];   // job A holds the block max (sorted)
    if (mk == 0) mk = S_;
    const int nkt = (mk + 63) >> 6;

    const int nktwa = (wavemax(vla == 0 ? S_ : vla) + 63) >> 6;
    const int nktwb = (wavemax(vlb == 0 ? S_ : vlb) + 63) >> 6;

    float ma = -3.0e38f, lsa = 0.f, mb = -3.0e38f, lsb = 0.f;
    f32x4 acca[4] = {}, accb[4] = {};   // acc[df][r] = out[q=l15][d = df*16 + 4*l4 + r]

    // per-tile compute for one job (inlined twice per tile)
    auto process = [&](int buf, int kt, const bf16x8& bq0, const bf16x8& bq1, int vlq,
                       float& m, float& lsum, f32x4 (&acc)[4]) {
        // --- QK^T swapped: S^T[k][q] ---
        f32x4 sc[4];
        __builtin_amdgcn_s_setprio(1);
        #pragma unroll
        for (int nf = 0; nf < 4; ++nf) {
            int kr = nf * 16 + l15, swz = kr & 7;
            bf16x8 ak0 = *(const bf16x8*)&kv(buf, 0)[kr * 64 + ((l4 ^ swz) * 8)];
            bf16x8 ak1 = *(const bf16x8*)&kv(buf, 0)[kr * 64 + (((l4 + 4) ^ swz) * 8)];
            f32x4 s = {0.f, 0.f, 0.f, 0.f};
            s = __builtin_amdgcn_mfma_f32_16x16x32_bf16(ak0, bq0, s, 0, 0, 0);
            s = __builtin_amdgcn_mfma_f32_16x16x32_bf16(ak1, bq1, s, 0, 0, 0);
            sc[nf] = s;
        }
        __builtin_amdgcn_s_setprio(0);

        // --- mask + online softmax (lane-local; q=l15-slot, k = kt*64 + nf*16 + 4*l4 + r) ---
        const int thr = vlq - kt * 64 - 4 * l4;
        float pv[16];
        float pm = -3.0e38f;
        if (__all(thr >= 52)) {
            #pragma unroll
            for (int nf = 0; nf < 4; ++nf)
                #pragma unroll
                for (int r = 0; r < 4; ++r) {
                    float y = sc[nf][r];
                    pv[nf * 4 + r] = y;
                    pm = fmaxf(pm, y);
                }
        } else {
            #pragma unroll
            for (int nf = 0; nf < 4; ++nf)
                #pragma unroll
                for (int r = 0; r < 4; ++r) {
                    float y = ((nf * 16 + r) < thr) ? sc[nf][r] : MASKVAL;
                    pv[nf * 4 + r] = y;
                    pm = fmaxf(pm, y);
                }
        }
        pm = fmaxf(pm, __shfl_xor(pm, 16, 64));
        pm = xor32max(pm);
        if (!__all(pm - m <= 8.0f)) {           // defer-max (T13)
            float mn = fmaxf(m, pm);
            float corr = __builtin_amdgcn_exp2f(m - mn);
            m = mn;
            lsum *= corr;
            #pragma unroll
            for (int df = 0; df < 4; ++df) acc[df] *= corr;
        }
        float rs = 0.f;
        #pragma unroll
        for (int i = 0; i < 16; ++i) {
            float e = __builtin_amdgcn_exp2f(pv[i] - m);
            pv[i] = e;
            rs += e;
        }
        rs += __shfl_xor(rs, 16, 64);
        rs = xor32add(rs);
        lsum += rs;

        // --- pack P -> bf16 pairs; redistribute to P^T B-fragments ---
        u32 pw[8];
        #pragma unroll
        for (int nf = 0; nf < 4; ++nf) {
            pw[2 * nf]     = cvtpk(pv[4 * nf + 0], pv[4 * nf + 1]);
            pw[2 * nf + 1] = cvtpk(pv[4 * nf + 2], pv[4 * nf + 3]);
        }
        U4 pb0, pb1;
        redist(pw[0], pw[2], pb0.u[0], pb0.u[2]);
        redist(pw[1], pw[3], pb0.u[1], pb0.u[3]);
        redist(pw[4], pw[6], pb1.u[0], pb1.u[2]);
        redist(pw[5], pw[7], pb1.u[1], pb1.u[3]);

        // --- PV swapped: out^T[d][q] += mfma(Vt_frag, P_frag) ---
        __builtin_amdgcn_s_setprio(1);
        #pragma unroll
        for (int df = 0; df < 4; ++df) {
            int vr = df * 16 + l15, swz = vr & 7;
            bf16x8 av0 = *(const bf16x8*)&kv(buf, 1)[vr * 64 + ((l4 ^ swz) * 8)];
            bf16x8 av1 = *(const bf16x8*)&kv(buf, 1)[vr * 64 + (((l4 + 4) ^ swz) * 8)];
            acc[df] = __builtin_amdgcn_mfma_f32_16x16x32_bf16(av0, pb0.v, acc[df], 0, 0, 0);
            acc[df] = __builtin_amdgcn_mfma_f32_16x16x32_bf16(av1, pb1.v, acc[df], 0, 0, 0);
        }
        __builtin_amdgcn_s_setprio(0);
    };

    stage(0, 0);
    __syncthreads();

    int buf = 0;
    for (int kt = 0; kt < nkt; ++kt) {
        if (kt + 1 < nkt) stage(buf ^ 1, kt + 1);
        if (kt < nktwa) process(buf, kt, bqa0, bqa1, vla, ma, lsa, acca);
        if (kt < nktwb) process(buf, kt, bqb0, bqb1, vlb, mb, lsb, accb);
        __syncthreads();
        buf ^= 1;
    }

    // --- epilogues: transpose acc through per-wave LDS region -> coalesced float4 stores ---
    // (no barriers: regions are per-wave-disjoint; intra-wave ds ordering via lgkmcnt)
    float* ep = (float*)smem_raw;          // per-wave region [16 q][68] f32 (8 waves = 34816 B)
    {
        const float inv = 1.0f / lsa;
        #pragma unroll
        for (int df = 0; df < 4; ++df)
            #pragma unroll
            for (int r = 0; r < 4; ++r)
                ep[w * 1088 + l15 * 68 + df * 16 + 4 * l4 + r] = acca[df][r] * inv;
        #pragma unroll
        for (int rr = 0; rr < 4; ++rr) {
            int row = l4 * 4 + rr;
            int qi2 = qidx[b * S_ + q0a + w * 16 + row];
            float4 vv = *(float4*)&ep[w * 1088 + row * 68 + l15 * 4];
            *(float4*)&out[((size_t)(b * S_ + qi2)) * D_ + h * 64 + l15 * 4] = vv;
        }
    }
    {
        const float inv = 1.0f / lsb;
        #pragma unroll
        for (int df = 0; df < 4; ++df)
            #pragma unroll
            for (int r = 0; r < 4; ++r)
                ep[w * 1088 + l15 * 68 + df * 16 + 4 * l4 + r] = accb[df][r] * inv;
        #pragma unroll
        for (int rr = 0; rr < 4; ++rr) {
            int row = l4 * 4 + rr;
            int qi2 = qidx[b * S_ + q0b + w * 16 + row];
            float4 vv = *(float4*)&ep[w * 1088 + row * 68 + l15 * 4];
            *(float4*)&out[((size_t)(b * S_ + qi2)) * D_ + h * 64 + l15 * 4] = vv;
        }
    }
}

extern "C" void kernel_launch(void* const* d_in, const int* in_sizes, int n_in,
                              void* d_out, int out_size, void* d_ws, size_t ws_size,
                              hipStream_t stream) {
    const float* query = (const float*)d_in[0];
    const float* key   = (const float*)d_in[1];
    const float* value = (const float*)d_in[2];
    const int*   vlen  = (const int*)d_in[3];
    const float* Wq    = (const float*)d_in[4];
    const float* Wk    = (const float*)d_in[5];
    const float* Wv    = (const float*)d_in[6];
    float* out = (float*)d_out;

    // workspace (~70 MB): wts 6 | vt 16 | qb kb | qidx 32KB
    char* ws = (char*)d_ws;
    const size_t MB = 1024 * 1024;
    const size_t TSZ = (size_t)B_ * S_ * D_ * 2;   // 16,777,216 B
    u16* wts = (u16*)(ws);                         // 3 x 1024x1024 bf16 (linear layout)
    u16* vt  = (u16*)(ws + 6 * MB);
    u16* qb  = (u16*)(ws + 6 * MB + TSZ);
    u16* kb  = (u16*)(ws + 6 * MB + 2 * TSZ);
    int* qidx = (int*)(ws + 6 * MB + 4 * TSZ);

    dim3 blk(256);

    transpose_w3_kernel<<<dim3(32, 32, 3), blk, 0, stream>>>(Wq, Wk, Wv, wts);
    sort_vlen_kernel<<<B_, dim3(1024), 0, stream>>>(vlen, qidx);

    gemm_qkv_kernel<<<dim3(64, 12), dim3(512), 0, stream>>>(query, key, value, wts, qb, kb, vt);

    attn_kernel<<<dim3(512), dim3(512), 0, stream>>>(qb, kb, vt, vlen, qidx, out);
}

// Round 19
// 138.739 us; speedup vs baseline: 1.0259x; 1.0259x over previous
//
#include <hip/hip_runtime.h>
#include <hip/hip_bf16.h>
#include <stdint.h>

// MHA: out = softmax_mask((X Wq)(X Wk)^T / sqrt(dh)) (X Wv), per-head, per-query valid_len mask.
// B=8 S=1024 D=1024 H=16 DH=64. f32 in/out, bf16 MFMA internally.
// R19 = R17 byte-exact revert (best measured: 138.2 us). R18's B reg-staging regressed
//      (4th failed conflict fix — conflicts are substantially hidden at this 2-phase structure).
//      Final pipeline: transpose_w3 + sort | fused QKV GEMM (BN=256, 8 waves, f32-A DMA,
//      V-transpose fused into epilogue) | attn (merged paired q-jobs, XCD-locality, sorted
//      vlen truncation, lane-local softmax, permlane P-redist).

#define B_  8
#define S_  1024
#define D_  1024
#define H_  16
#define DH_ 64

typedef short bf16x8 __attribute__((ext_vector_type(8)));
typedef float f32x4  __attribute__((ext_vector_type(4)));
typedef unsigned short u16;
typedef uint32_t u32;
typedef u16 u16x8 __attribute__((ext_vector_type(8)));
typedef u16 u16x4 __attribute__((ext_vector_type(4)));

#define MASKVAL  (-1442.6950408889634f)            // -1000 * log2(e)
#define QSCALE   (0.18033688011112042f)            // (1/sqrt(64)) * log2(e)

union U4 { u32 u[4]; bf16x8 v; };

__device__ __forceinline__ u16 f2bf(float f) {
    union { float f; uint32_t u; } v; v.f = f;
    uint32_t u = v.u;
    return (u16)((u + 0x7FFFu + ((u >> 16) & 1u)) >> 16);   // RNE
}

__device__ __forceinline__ u32 cvtpk(float lo, float hi) {
    u32 r;
    asm("v_cvt_pk_bf16_f32 %0, %1, %2" : "=v"(r) : "v"(lo), "v"(hi));
    return r;
}

__device__ __forceinline__ void gload16(const void* g, const void* l) {
    __builtin_amdgcn_global_load_lds(
        (const __attribute__((address_space(1))) void*)g,
        (__attribute__((address_space(3))) void*)l, 16, 0, 0);
}

// xor-32 reductions via v_permlane32_swap (VALU pipe, not LDS).
__device__ __forceinline__ float xor32max(float v) {
    float a = v, b = v;
    asm volatile("" : "+v"(b));
    asm("v_permlane32_swap_b32 %0, %1" : "+v"(a), "+v"(b));
    return fmaxf(a, b);
}
__device__ __forceinline__ float xor32add(float v) {
    float a = v, b = v;
    asm volatile("" : "+v"(b));
    asm("v_permlane32_swap_b32 %0, %1" : "+v"(a), "+v"(b));
    return a + b;
}

// ---------------- W[k][n] f32 -> Wt[n][k] bf16 (linear layout), z selects {Wq,Wk,Wv} ----------------
__global__ void transpose_w3_kernel(const float* __restrict__ Wq, const float* __restrict__ Wk,
                                    const float* __restrict__ Wv, u16* __restrict__ Wts) {
    __shared__ u16 tile[32 * 33];
    const int z = blockIdx.z;
    const float* W = (z == 0) ? Wq : (z == 1) ? Wk : Wv;
    u16* Wt = Wts + (size_t)z * D_ * D_;
    int k0 = blockIdx.y * 32, n0 = blockIdx.x * 32;
    int t = threadIdx.x;
    int c = t & 31;
    for (int p = 0; p < 4; ++p) {
        int r = p * 8 + (t >> 5);
        tile[r * 33 + c] = f2bf(W[(size_t)(k0 + r) * D_ + n0 + c]);
    }
    __syncthreads();
    int rn = t >> 3, c4 = t & 7;
    u16x4 v;
    for (int j = 0; j < 4; ++j) v[j] = tile[(c4 * 4 + j) * 33 + rn];
    *(u16x4*)(Wt + (size_t)(n0 + rn) * D_ + k0 + c4 * 4) = v;
}

// ---------------- per-batch bitonic sort of q-rows by valid_len (0 -> S, sorted last) ----------------
__global__ __launch_bounds__(1024) void sort_vlen_kernel(const int* __restrict__ vlen,
                                                         int* __restrict__ qidx) {
    __shared__ u32 sk[1024];
    const int b = blockIdx.x, t = threadIdx.x;
    int k = vlen[b * S_ + t];
    u32 key = (k == 0) ? (u32)S_ : (u32)k;
    sk[t] = (key << 10) | (u32)t;
    __syncthreads();
    for (int sz = 2; sz <= 1024; sz <<= 1) {
        for (int st = sz >> 1; st > 0; st >>= 1) {
            int j = t ^ st;
            if (j > t) {
                u32 a = sk[t], c = sk[j];
                bool des = (t & sz) != 0;
                if ((a > c) != des) { sk[t] = c; sk[j] = a; }
            }
            __syncthreads();
        }
    }
    qidx[b * S_ + t] = (int)(sk[t] & 1023u);
}

// ---------------- fused QKV GEMM, BN=256 at 8 waves; V writes vt directly ----------------
// grid (64, 12); y -> (z = y>>2, n0 = (y&3)*256). 128(M)x256(N) tile, BK=32, 512 threads.
// Wave grid 2x4: wr = w>>2 (M), wc = w&3 (N); each wave 64x64, acc[4][4].
// z<2: C[m][n] bf16 (qb/kb). z==2: LDS-transpose the tile and write vt[(b*1024+n)*1024+s]
// (derivation: vt[((b*16+h)*64+d)*1024+s] with n = h*64+d collapses to b*1024+n).
__global__ __launch_bounds__(512, 4) void gemm_qkv_kernel(const float* __restrict__ Aq,
                                                          const float* __restrict__ Ak,
                                                          const float* __restrict__ Av,
                                                          const u16* __restrict__ wts,
                                                          u16* __restrict__ qb, u16* __restrict__ kb,
                                                          u16* __restrict__ vt) {
    __shared__ __align__(16) char smem_g[65536];
    float* lds_a = (float*)smem_g;            // [2][128*32] f32 = 2 x 16 KB
    u16*  lds_b = (u16*)(smem_g + 32768);     // [2][256*32] u16 = 2 x 16 KB
    const int zy = blockIdx.y;
    const int z = zy >> 2;
    const float* A = (z == 0) ? Aq : (z == 1) ? Ak : Av;
    const u16* Bt = wts + (size_t)z * D_ * D_;
    u16* C = (z == 0) ? qb : (z == 1) ? kb : vt;
    const float cmul = (z == 0) ? QSCALE : 1.0f;

    const int t = threadIdx.x, w = t >> 6, l = t & 63;
    const int m0 = blockIdx.x * 128, n0 = (zy & 3) * 256;
    const int wr = w >> 2, wc = w & 3;
    const int l15 = l & 15, l4 = l >> 4;
    f32x4 acc[4][4] = {};

    auto stage = [&](int buf, int kt) {
        int k0 = kt * 32;
        #pragma unroll
        for (int i = 0; i < 2; ++i) {
            int c = i * 512 + t;
            int row = c >> 3, xs = (c & 7) ^ (row & 7);
            gload16(A + (size_t)(m0 + row) * D_ + k0 + xs * 4, &lds_a[buf * 4096 + c * 4]);
        }
        #pragma unroll
        for (int i = 0; i < 2; ++i) {
            int c = i * 512 + t;
            int row = c >> 2, x = c & 3;
            gload16(Bt + (size_t)(n0 + row) * D_ + k0 + x * 8, &lds_b[buf * 8192 + c * 8]);
        }
    };

    stage(0, 0);
    __syncthreads();
    int buf = 0;
    for (int kt = 0; kt < 32; ++kt) {
        if (kt + 1 < 32) stage(buf ^ 1, kt + 1);
        bf16x8 af[4], bfr[4];
        #pragma unroll
        for (int mi = 0; mi < 4; ++mi) {
            int r = wr * 64 + mi * 16 + l15;
            int c0 = (l4 * 2) ^ (r & 7), c1 = (l4 * 2 + 1) ^ (r & 7);
            float4 fa0 = *(const float4*)&lds_a[buf * 4096 + r * 32 + c0 * 4];
            float4 fa1 = *(const float4*)&lds_a[buf * 4096 + r * 32 + c1 * 4];
            U4 d;
            d.u[0] = cvtpk(fa0.x, fa0.y); d.u[1] = cvtpk(fa0.z, fa0.w);
            d.u[2] = cvtpk(fa1.x, fa1.y); d.u[3] = cvtpk(fa1.z, fa1.w);
            af[mi] = d.v;
        }
        #pragma unroll
        for (int ni = 0; ni < 4; ++ni) {
            int r = wc * 64 + ni * 16 + l15;
            bfr[ni] = *(const bf16x8*)&lds_b[buf * 8192 + r * 32 + l4 * 8];
        }
        #pragma unroll
        for (int mi = 0; mi < 4; ++mi)
            #pragma unroll
            for (int ni = 0; ni < 4; ++ni)
                acc[mi][ni] = __builtin_amdgcn_mfma_f32_16x16x32_bf16(af[mi], bfr[ni], acc[mi][ni], 0, 0, 0);
        __syncthreads();
        buf ^= 1;
    }

    if (z == 2) {
        // V: LDS-transpose tile -> vt. T[256 n][128 m] u16, m-chunk XOR-swizzled by (n&7).
        u16* T = (u16*)smem_g;   // 64 KB exactly
        #pragma unroll
        for (int mi = 0; mi < 4; ++mi)
            #pragma unroll
            for (int ni = 0; ni < 4; ++ni)
                #pragma unroll
                for (int r = 0; r < 4; ++r) {
                    int nl = wc * 64 + ni * 16 + l15;
                    int ml = wr * 64 + mi * 16 + l4 * 4 + r;
                    T[nl * 128 + (ml ^ ((nl & 7) << 3))] = f2bf(acc[mi][ni][r] * cmul);
                }
        __syncthreads();
        const int nr = t >> 1, hf = t & 1;
        const size_t vbase = ((size_t)((m0 >> 10) * 1024 + n0 + nr)) * 1024 + (m0 & 1023) + hf * 64;
        #pragma unroll
        for (int c = 0; c < 8; ++c) {
            int cm = hf * 8 + c;
            u16x8 vv = *(u16x8*)&T[nr * 128 + ((cm ^ (nr & 7)) * 8)];
            *(u16x8*)&C[vbase + c * 8] = vv;
        }
    } else {
        // epilogue: C/D layout col=lane&15, row=(lane>>4)*4+reg (m89-verified)
        #pragma unroll
        for (int mi = 0; mi < 4; ++mi)
            #pragma unroll
            for (int ni = 0; ni < 4; ++ni)
                #pragma unroll
                for (int r = 0; r < 4; ++r) {
                    int m = m0 + wr * 64 + mi * 16 + l4 * 4 + r;
                    int n = n0 + wc * 64 + ni * 16 + l15;
                    C[(size_t)m * D_ + n] = f2bf(acc[mi][ni][r] * cmul);
                }
    }
}

// ---------------- flash attention: 8 waves x 16q, MERGED paired q-jobs, XCD-locality (R10) ---------
// 512 blocks: n&7 = XCD slot; j = n>>3: bh = (n&7) + 8*(j>>2), pair p = j&3.
// ONE k-loop over nkt(qblk 7-p) tiles; each tile staged once and consumed by BOTH jobs
// (qblk 7-p and qblk p), each guarded by its per-wave nktw (skipped tiles contribute exactly 0).
__global__ __launch_bounds__(512) void attn_kernel(const u16* __restrict__ qb,
                                                   const u16* __restrict__ kb,
                                                   const u16* __restrict__ vt,
                                                   const int* __restrict__ vlen,
                                                   const int* __restrict__ qidx,
                                                   float* __restrict__ out) {
    __shared__ __align__(16) char smem_raw[34816];   // stage 2x(8K K + 8K Vt) = 32K; epilogue 34K
    auto kv = [&](int buf, int which) -> u16* {
        return (u16*)(smem_raw + buf * 16384 + which * 8192);
    };

    const int t = threadIdx.x, w = t >> 6, l = t & 63;
    const int n = blockIdx.x;
    const int x = n & 7, j = n >> 3;
    const int bh = x + 8 * (j >> 2);
    const int p = j & 3;
    const int b = bh >> 4, h = bh & 15;
    const int l15 = l & 15, l4 = l >> 4;
    const bool rowe = ((l & 16) == 0);

    const u16* kbase = kb + ((size_t)(b * S_)) * D_ + h * 64;
    const u16* vbase = vt + ((size_t)bh * 64) * (size_t)S_;

    // 512 threads: one 16B chunk of K and one of Vt each per tile (source-swizzled)
    const int kr_s = t >> 3, x_s = (t & 7) ^ (kr_s & 7);
    auto stage = [&](int buf, int kt) {
        gload16(kbase + (size_t)(kt * 64 + kr_s) * D_ + x_s * 8, &kv(buf, 0)[t * 8]);
        gload16(vbase + (size_t)kr_s * S_ + kt * 64 + x_s * 8, &kv(buf, 1)[t * 8]);
    };

    // P-redistribution: permlane32_swap + xor16 shuffle
    auto redist = [&](u32 P, u32 Q, u32& oe, u32& oo) {
        u32 X = P, Y = Q;
        asm("v_permlane32_swap_b32 %0, %1" : "+v"(X), "+v"(Y));
        u32 t1 = (u32)__shfl_xor((int)Y, 16, 64);
        u32 t2 = (u32)__shfl_xor((int)X, 16, 64);
        oe = rowe ? X : t1;
        oo = rowe ? t2 : Y;
    };

    auto wavemax = [&](int v) {
        int s1 = __shfl_xor(v, 1, 64);  v = v > s1 ? v : s1;
        int s2 = __shfl_xor(v, 2, 64);  v = v > s2 ? v : s2;
        int s4 = __shfl_xor(v, 4, 64);  v = v > s4 ? v : s4;
        int s8 = __shfl_xor(v, 8, 64);  v = v > s8 ? v : s8;
        return v;
    };

    const int q0a = (7 - p) * 128, q0b = p * 128;

    const int qia = qidx[b * S_ + q0a + w * 16 + l15];
    const u16* qpa = qb + ((size_t)(b * S_ + qia)) * D_ + h * 64 + l4 * 8;
    const bf16x8 bqa0 = *(const bf16x8*)qpa;
    const bf16x8 bqa1 = *(const bf16x8*)(qpa + 32);
    const int vla = vlen[b * S_ + qia];

    const int qib = qidx[b * S_ + q0b + w * 16 + l15];
    const u16* qpb = qb + ((size_t)(b * S_ + qib)) * D_ + h * 64 + l4 * 8;
    const bf16x8 bqb0 = *(const bf16x8*)qpb;
    const bf16x8 bqb1 = *(const bf16x8*)(qpb + 32);
    const int vlb = vlen[b * S_ + qib];

    int mk = vlen[b * S_ + qidx[b * S_ + q0a + 127]];   // job A holds the block max (sorted)
    if (mk == 0) mk = S_;
    const int nkt = (mk + 63) >> 6;

    const int nktwa = (wavemax(vla == 0 ? S_ : vla) + 63) >> 6;
    const int nktwb = (wavemax(vlb == 0 ? S_ : vlb) + 63) >> 6;

    float ma = -3.0e38f, lsa = 0.f, mb = -3.0e38f, lsb = 0.f;
    f32x4 acca[4] = {}, accb[4] = {};   // acc[df][r] = out[q=l15][d = df*16 + 4*l4 + r]

    // per-tile compute for one job (inlined twice per tile)
    auto process = [&](int buf, int kt, const bf16x8& bq0, const bf16x8& bq1, int vlq,
                       float& m, float& lsum, f32x4 (&acc)[4]) {
        // --- QK^T swapped: S^T[k][q] ---
        f32x4 sc[4];
        __builtin_amdgcn_s_setprio(1);
        #pragma unroll
        for (int nf = 0; nf < 4; ++nf) {
            int kr = nf * 16 + l15, swz = kr & 7;
            bf16x8 ak0 = *(const bf16x8*)&kv(buf, 0)[kr * 64 + ((l4 ^ swz) * 8)];
            bf16x8 ak1 = *(const bf16x8*)&kv(buf, 0)[kr * 64 + (((l4 + 4) ^ swz) * 8)];
            f32x4 s = {0.f, 0.f, 0.f, 0.f};
            s = __builtin_amdgcn_mfma_f32_16x16x32_bf16(ak0, bq0, s, 0, 0, 0);
            s = __builtin_amdgcn_mfma_f32_16x16x32_bf16(ak1, bq1, s, 0, 0, 0);
            sc[nf] = s;
        }
        __builtin_amdgcn_s_setprio(0);

        // --- mask + online softmax (lane-local; q=l15-slot, k = kt*64 + nf*16 + 4*l4 + r) ---
        const int thr = vlq - kt * 64 - 4 * l4;
        float pv[16];
        float pm = -3.0e38f;
        if (__all(thr >= 52)) {
            #pragma unroll
            for (int nf = 0; nf < 4; ++nf)
                #pragma unroll
                for (int r = 0; r < 4; ++r) {
                    float y = sc[nf][r];
                    pv[nf * 4 + r] = y;
                    pm = fmaxf(pm, y);
                }
        } else {
            #pragma unroll
            for (int nf = 0; nf < 4; ++nf)
                #pragma unroll
                for (int r = 0; r < 4; ++r) {
                    float y = ((nf * 16 + r) < thr) ? sc[nf][r] : MASKVAL;
                    pv[nf * 4 + r] = y;
                    pm = fmaxf(pm, y);
                }
        }
        pm = fmaxf(pm, __shfl_xor(pm, 16, 64));
        pm = xor32max(pm);
        if (!__all(pm - m <= 8.0f)) {           // defer-max (T13)
            float mn = fmaxf(m, pm);
            float corr = __builtin_amdgcn_exp2f(m - mn);
            m = mn;
            lsum *= corr;
            #pragma unroll
            for (int df = 0; df < 4; ++df) acc[df] *= corr;
        }
        float rs = 0.f;
        #pragma unroll
        for (int i = 0; i < 16; ++i) {
            float e = __builtin_amdgcn_exp2f(pv[i] - m);
            pv[i] = e;
            rs += e;
        }
        rs += __shfl_xor(rs, 16, 64);
        rs = xor32add(rs);
        lsum += rs;

        // --- pack P -> bf16 pairs; redistribute to P^T B-fragments ---
        u32 pw[8];
        #pragma unroll
        for (int nf = 0; nf < 4; ++nf) {
            pw[2 * nf]     = cvtpk(pv[4 * nf + 0], pv[4 * nf + 1]);
            pw[2 * nf + 1] = cvtpk(pv[4 * nf + 2], pv[4 * nf + 3]);
        }
        U4 pb0, pb1;
        redist(pw[0], pw[2], pb0.u[0], pb0.u[2]);
        redist(pw[1], pw[3], pb0.u[1], pb0.u[3]);
        redist(pw[4], pw[6], pb1.u[0], pb1.u[2]);
        redist(pw[5], pw[7], pb1.u[1], pb1.u[3]);

        // --- PV swapped: out^T[d][q] += mfma(Vt_frag, P_frag) ---
        __builtin_amdgcn_s_setprio(1);
        #pragma unroll
        for (int df = 0; df < 4; ++df) {
            int vr = df * 16 + l15, swz = vr & 7;
            bf16x8 av0 = *(const bf16x8*)&kv(buf, 1)[vr * 64 + ((l4 ^ swz) * 8)];
            bf16x8 av1 = *(const bf16x8*)&kv(buf, 1)[vr * 64 + (((l4 + 4) ^ swz) * 8)];
            acc[df] = __builtin_amdgcn_mfma_f32_16x16x32_bf16(av0, pb0.v, acc[df], 0, 0, 0);
            acc[df] = __builtin_amdgcn_mfma_f32_16x16x32_bf16(av1, pb1.v, acc[df], 0, 0, 0);
        }
        __builtin_amdgcn_s_setprio(0);
    };

    stage(0, 0);
    __syncthreads();

    int buf = 0;
    for (int kt = 0; kt < nkt; ++kt) {
        if (kt + 1 < nkt) stage(buf ^ 1, kt + 1);
        if (kt < nktwa) process(buf, kt, bqa0, bqa1, vla, ma, lsa, acca);
        if (kt < nktwb) process(buf, kt, bqb0, bqb1, vlb, mb, lsb, accb);
        __syncthreads();
        buf ^= 1;
    }

    // --- epilogues: transpose acc through per-wave LDS region -> coalesced float4 stores ---
    // (no barriers: regions are per-wave-disjoint; intra-wave ds ordering via lgkmcnt)
    float* ep = (float*)smem_raw;          // per-wave region [16 q][68] f32 (8 waves = 34816 B)
    {
        const float inv = 1.0f / lsa;
        #pragma unroll
        for (int df = 0; df < 4; ++df)
            #pragma unroll
            for (int r = 0; r < 4; ++r)
                ep[w * 1088 + l15 * 68 + df * 16 + 4 * l4 + r] = acca[df][r] * inv;
        #pragma unroll
        for (int rr = 0; rr < 4; ++rr) {
            int row = l4 * 4 + rr;
            int qi2 = qidx[b * S_ + q0a + w * 16 + row];
            float4 vv = *(float4*)&ep[w * 1088 + row * 68 + l15 * 4];
            *(float4*)&out[((size_t)(b * S_ + qi2)) * D_ + h * 64 + l15 * 4] = vv;
        }
    }
    {
        const float inv = 1.0f / lsb;
        #pragma unroll
        for (int df = 0; df < 4; ++df)
            #pragma unroll
            for (int r = 0; r < 4; ++r)
                ep[w * 1088 + l15 * 68 + df * 16 + 4 * l4 + r] = accb[df][r] * inv;
        #pragma unroll
        for (int rr = 0; rr < 4; ++rr) {
            int row = l4 * 4 + rr;
            int qi2 = qidx[b * S_ + q0b + w * 16 + row];
            float4 vv = *(float4*)&ep[w * 1088 + row * 68 + l15 * 4];
            *(float4*)&out[((size_t)(b * S_ + qi2)) * D_ + h * 64 + l15 * 4] = vv;
        }
    }
}

extern "C" void kernel_launch(void* const* d_in, const int* in_sizes, int n_in,
                              void* d_out, int out_size, void* d_ws, size_t ws_size,
                              hipStream_t stream) {
    const float* query = (const float*)d_in[0];
    const float* key   = (const float*)d_in[1];
    const float* value = (const float*)d_in[2];
    const int*   vlen  = (const int*)d_in[3];
    const float* Wq    = (const float*)d_in[4];
    const float* Wk    = (const float*)d_in[5];
    const float* Wv    = (const float*)d_in[6];
    float* out = (float*)d_out;

    // workspace (~70 MB): wts 6 | vt 16 | qb kb | qidx 32KB
    char* ws = (char*)d_ws;
    const size_t MB = 1024 * 1024;
    const size_t TSZ = (size_t)B_ * S_ * D_ * 2;   // 16,777,216 B
    u16* wts = (u16*)(ws);                         // 3 x 1024x1024 bf16 (linear layout)
    u16* vt  = (u16*)(ws + 6 * MB);
    u16* qb  = (u16*)(ws + 6 * MB + TSZ);
    u16* kb  = (u16*)(ws + 6 * MB + 2 * TSZ);
    int* qidx = (int*)(ws + 6 * MB + 4 * TSZ);

    dim3 blk(256);

    transpose_w3_kernel<<<dim3(32, 32, 3), blk, 0, stream>>>(Wq, Wk, Wv, wts);
    sort_vlen_kernel<<<B_, dim3(1024), 0, stream>>>(vlen, qidx);

    gemm_qkv_kernel<<<dim3(64, 12), dim3(512), 0, stream>>>(query, key, value, wts, qb, kb, vt);

    attn_kernel<<<dim3(512), dim3(512), 0, stream>>>(qb, kb, vt, vlen, qidx, out);
}

// Round 20
// 138.023 us; speedup vs baseline: 1.0312x; 1.0052x over previous
//
#include <hip/hip_runtime.h>
#include <hip/hip_bf16.h>
#include <stdint.h>

// MHA: out = softmax_mask((X Wq)(X Wk)^T / sqrt(dh)) (X Wv), per-head, per-query valid_len mask.
// B=8 S=1024 D=1024 H=16 DH=64. f32 in/out, bf16 MFMA internally.
// R20 = R17/R19 + cvtpk-pair epilogues in the GEMM (z<2: 32 cvtpk + shift-extract stores;
//      z==2: 32 cvtpk + 32 ds_write_b32 into the vt-transpose tile). Saves ~200 VALU/thread
//      of scalar f2bf in the once-per-block epilogue. Everything else byte-identical to R19.

#define B_  8
#define S_  1024
#define D_  1024
#define H_  16
#define DH_ 64

typedef short bf16x8 __attribute__((ext_vector_type(8)));
typedef float f32x4  __attribute__((ext_vector_type(4)));
typedef unsigned short u16;
typedef uint32_t u32;
typedef u16 u16x8 __attribute__((ext_vector_type(8)));
typedef u16 u16x4 __attribute__((ext_vector_type(4)));

#define MASKVAL  (-1442.6950408889634f)            // -1000 * log2(e)
#define QSCALE   (0.18033688011112042f)            // (1/sqrt(64)) * log2(e)

union U4 { u32 u[4]; bf16x8 v; };

__device__ __forceinline__ u16 f2bf(float f) {
    union { float f; uint32_t u; } v; v.f = f;
    uint32_t u = v.u;
    return (u16)((u + 0x7FFFu + ((u >> 16) & 1u)) >> 16);   // RNE
}

__device__ __forceinline__ u32 cvtpk(float lo, float hi) {
    u32 r;
    asm("v_cvt_pk_bf16_f32 %0, %1, %2" : "=v"(r) : "v"(lo), "v"(hi));
    return r;
}

__device__ __forceinline__ void gload16(const void* g, const void* l) {
    __builtin_amdgcn_global_load_lds(
        (const __attribute__((address_space(1))) void*)g,
        (__attribute__((address_space(3))) void*)l, 16, 0, 0);
}

// xor-32 reductions via v_permlane32_swap (VALU pipe, not LDS).
__device__ __forceinline__ float xor32max(float v) {
    float a = v, b = v;
    asm volatile("" : "+v"(b));
    asm("v_permlane32_swap_b32 %0, %1" : "+v"(a), "+v"(b));
    return fmaxf(a, b);
}
__device__ __forceinline__ float xor32add(float v) {
    float a = v, b = v;
    asm volatile("" : "+v"(b));
    asm("v_permlane32_swap_b32 %0, %1" : "+v"(a), "+v"(b));
    return a + b;
}

// ---------------- W[k][n] f32 -> Wt[n][k] bf16 (linear layout), z selects {Wq,Wk,Wv} ----------------
__global__ void transpose_w3_kernel(const float* __restrict__ Wq, const float* __restrict__ Wk,
                                    const float* __restrict__ Wv, u16* __restrict__ Wts) {
    __shared__ u16 tile[32 * 33];
    const int z = blockIdx.z;
    const float* W = (z == 0) ? Wq : (z == 1) ? Wk : Wv;
    u16* Wt = Wts + (size_t)z * D_ * D_;
    int k0 = blockIdx.y * 32, n0 = blockIdx.x * 32;
    int t = threadIdx.x;
    int c = t & 31;
    for (int p = 0; p < 4; ++p) {
        int r = p * 8 + (t >> 5);
        tile[r * 33 + c] = f2bf(W[(size_t)(k0 + r) * D_ + n0 + c]);
    }
    __syncthreads();
    int rn = t >> 3, c4 = t & 7;
    u16x4 v;
    for (int j = 0; j < 4; ++j) v[j] = tile[(c4 * 4 + j) * 33 + rn];
    *(u16x4*)(Wt + (size_t)(n0 + rn) * D_ + k0 + c4 * 4) = v;
}

// ---------------- per-batch bitonic sort of q-rows by valid_len (0 -> S, sorted last) ----------------
__global__ __launch_bounds__(1024) void sort_vlen_kernel(const int* __restrict__ vlen,
                                                         int* __restrict__ qidx) {
    __shared__ u32 sk[1024];
    const int b = blockIdx.x, t = threadIdx.x;
    int k = vlen[b * S_ + t];
    u32 key = (k == 0) ? (u32)S_ : (u32)k;
    sk[t] = (key << 10) | (u32)t;
    __syncthreads();
    for (int sz = 2; sz <= 1024; sz <<= 1) {
        for (int st = sz >> 1; st > 0; st >>= 1) {
            int j = t ^ st;
            if (j > t) {
                u32 a = sk[t], c = sk[j];
                bool des = (t & sz) != 0;
                if ((a > c) != des) { sk[t] = c; sk[j] = a; }
            }
            __syncthreads();
        }
    }
    qidx[b * S_ + t] = (int)(sk[t] & 1023u);
}

// ---------------- fused QKV GEMM, BN=256 at 8 waves; V writes vt directly ----------------
// grid (64, 12); y -> (z = y>>2, n0 = (y&3)*256). 128(M)x256(N) tile, BK=32, 512 threads.
// Wave grid 2x4: wr = w>>2 (M), wc = w&3 (N); each wave 64x64, acc[4][4].
// z<2: C[m][n] bf16 (qb/kb), cvtpk-pair epilogue. z==2: LDS-transpose tile -> vt.
__global__ __launch_bounds__(512, 4) void gemm_qkv_kernel(const float* __restrict__ Aq,
                                                          const float* __restrict__ Ak,
                                                          const float* __restrict__ Av,
                                                          const u16* __restrict__ wts,
                                                          u16* __restrict__ qb, u16* __restrict__ kb,
                                                          u16* __restrict__ vt) {
    __shared__ __align__(16) char smem_g[65536];
    float* lds_a = (float*)smem_g;            // [2][128*32] f32 = 2 x 16 KB
    u16*  lds_b = (u16*)(smem_g + 32768);     // [2][256*32] u16 = 2 x 16 KB
    const int zy = blockIdx.y;
    const int z = zy >> 2;
    const float* A = (z == 0) ? Aq : (z == 1) ? Ak : Av;
    const u16* Bt = wts + (size_t)z * D_ * D_;
    u16* C = (z == 0) ? qb : (z == 1) ? kb : vt;
    const float cmul = (z == 0) ? QSCALE : 1.0f;

    const int t = threadIdx.x, w = t >> 6, l = t & 63;
    const int m0 = blockIdx.x * 128, n0 = (zy & 3) * 256;
    const int wr = w >> 2, wc = w & 3;
    const int l15 = l & 15, l4 = l >> 4;
    f32x4 acc[4][4] = {};

    auto stage = [&](int buf, int kt) {
        int k0 = kt * 32;
        #pragma unroll
        for (int i = 0; i < 2; ++i) {
            int c = i * 512 + t;
            int row = c >> 3, xs = (c & 7) ^ (row & 7);
            gload16(A + (size_t)(m0 + row) * D_ + k0 + xs * 4, &lds_a[buf * 4096 + c * 4]);
        }
        #pragma unroll
        for (int i = 0; i < 2; ++i) {
            int c = i * 512 + t;
            int row = c >> 2, x = c & 3;
            gload16(Bt + (size_t)(n0 + row) * D_ + k0 + x * 8, &lds_b[buf * 8192 + c * 8]);
        }
    };

    stage(0, 0);
    __syncthreads();
    int buf = 0;
    for (int kt = 0; kt < 32; ++kt) {
        if (kt + 1 < 32) stage(buf ^ 1, kt + 1);
        bf16x8 af[4], bfr[4];
        #pragma unroll
        for (int mi = 0; mi < 4; ++mi) {
            int r = wr * 64 + mi * 16 + l15;
            int c0 = (l4 * 2) ^ (r & 7), c1 = (l4 * 2 + 1) ^ (r & 7);
            float4 fa0 = *(const float4*)&lds_a[buf * 4096 + r * 32 + c0 * 4];
            float4 fa1 = *(const float4*)&lds_a[buf * 4096 + r * 32 + c1 * 4];
            U4 d;
            d.u[0] = cvtpk(fa0.x, fa0.y); d.u[1] = cvtpk(fa0.z, fa0.w);
            d.u[2] = cvtpk(fa1.x, fa1.y); d.u[3] = cvtpk(fa1.z, fa1.w);
            af[mi] = d.v;
        }
        #pragma unroll
        for (int ni = 0; ni < 4; ++ni) {
            int r = wc * 64 + ni * 16 + l15;
            bfr[ni] = *(const bf16x8*)&lds_b[buf * 8192 + r * 32 + l4 * 8];
        }
        #pragma unroll
        for (int mi = 0; mi < 4; ++mi)
            #pragma unroll
            for (int ni = 0; ni < 4; ++ni)
                acc[mi][ni] = __builtin_amdgcn_mfma_f32_16x16x32_bf16(af[mi], bfr[ni], acc[mi][ni], 0, 0, 0);
        __syncthreads();
        buf ^= 1;
    }

    if (z == 2) {
        // V: LDS-transpose tile -> vt. T[256 n][128 m] u16, m-chunk XOR-swizzled by (n&7).
        // cvtpk packs (r, r+1) m-adjacent pairs -> one ds_write_b32 (aligned: ml0%4==0, sw bits>=3).
        u16* T = (u16*)smem_g;   // 64 KB exactly
        #pragma unroll
        for (int mi = 0; mi < 4; ++mi)
            #pragma unroll
            for (int ni = 0; ni < 4; ++ni) {
                int nl = wc * 64 + ni * 16 + l15;
                int ml0 = wr * 64 + mi * 16 + l4 * 4;
                int sw = (nl & 7) << 3;
                u32 p0 = cvtpk(acc[mi][ni][0] * cmul, acc[mi][ni][1] * cmul);
                u32 p1 = cvtpk(acc[mi][ni][2] * cmul, acc[mi][ni][3] * cmul);
                *(u32*)&T[nl * 128 + (ml0 ^ sw)] = p0;
                *(u32*)&T[nl * 128 + ((ml0 + 2) ^ sw)] = p1;
            }
        __syncthreads();
        const int nr = t >> 1, hf = t & 1;
        const size_t vbase = ((size_t)((m0 >> 10) * 1024 + n0 + nr)) * 1024 + (m0 & 1023) + hf * 64;
        #pragma unroll
        for (int c = 0; c < 8; ++c) {
            int cm = hf * 8 + c;
            u16x8 vv = *(u16x8*)&T[nr * 128 + ((cm ^ (nr & 7)) * 8)];
            *(u16x8*)&C[vbase + c * 8] = vv;
        }
    } else {
        // epilogue: C/D layout col=lane&15, row=(lane>>4)*4+reg (m89-verified);
        // cvtpk converts (r, r+1) pairs, halves extracted for the two row stores.
        #pragma unroll
        for (int mi = 0; mi < 4; ++mi)
            #pragma unroll
            for (int ni = 0; ni < 4; ++ni) {
                int m = m0 + wr * 64 + mi * 16 + l4 * 4;
                int n = n0 + wc * 64 + ni * 16 + l15;
                u32 p0 = cvtpk(acc[mi][ni][0] * cmul, acc[mi][ni][1] * cmul);
                u32 p1 = cvtpk(acc[mi][ni][2] * cmul, acc[mi][ni][3] * cmul);
                C[(size_t)m * D_ + n]       = (u16)p0;
                C[(size_t)(m + 1) * D_ + n] = (u16)(p0 >> 16);
                C[(size_t)(m + 2) * D_ + n] = (u16)p1;
                C[(size_t)(m + 3) * D_ + n] = (u16)(p1 >> 16);
            }
    }
}

// ---------------- flash attention: 8 waves x 16q, MERGED paired q-jobs, XCD-locality (R10) ---------
// 512 blocks: n&7 = XCD slot; j = n>>3: bh = (n&7) + 8*(j>>2), pair p = j&3.
// ONE k-loop over nkt(qblk 7-p) tiles; each tile staged once and consumed by BOTH jobs
// (qblk 7-p and qblk p), each guarded by its per-wave nktw (skipped tiles contribute exactly 0).
__global__ __launch_bounds__(512) void attn_kernel(const u16* __restrict__ qb,
                                                   const u16* __restrict__ kb,
                                                   const u16* __restrict__ vt,
                                                   const int* __restrict__ vlen,
                                                   const int* __restrict__ qidx,
                                                   float* __restrict__ out) {
    __shared__ __align__(16) char smem_raw[34816];   // stage 2x(8K K + 8K Vt) = 32K; epilogue 34K
    auto kv = [&](int buf, int which) -> u16* {
        return (u16*)(smem_raw + buf * 16384 + which * 8192);
    };

    const int t = threadIdx.x, w = t >> 6, l = t & 63;
    const int n = blockIdx.x;
    const int x = n & 7, j = n >> 3;
    const int bh = x + 8 * (j >> 2);
    const int p = j & 3;
    const int b = bh >> 4, h = bh & 15;
    const int l15 = l & 15, l4 = l >> 4;
    const bool rowe = ((l & 16) == 0);

    const u16* kbase = kb + ((size_t)(b * S_)) * D_ + h * 64;
    const u16* vbase = vt + ((size_t)bh * 64) * (size_t)S_;

    // 512 threads: one 16B chunk of K and one of Vt each per tile (source-swizzled)
    const int kr_s = t >> 3, x_s = (t & 7) ^ (kr_s & 7);
    auto stage = [&](int buf, int kt) {
        gload16(kbase + (size_t)(kt * 64 + kr_s) * D_ + x_s * 8, &kv(buf, 0)[t * 8]);
        gload16(vbase + (size_t)kr_s * S_ + kt * 64 + x_s * 8, &kv(buf, 1)[t * 8]);
    };

    // P-redistribution: permlane32_swap + xor16 shuffle
    auto redist = [&](u32 P, u32 Q, u32& oe, u32& oo) {
        u32 X = P, Y = Q;
        asm("v_permlane32_swap_b32 %0, %1" : "+v"(X), "+v"(Y));
        u32 t1 = (u32)__shfl_xor((int)Y, 16, 64);
        u32 t2 = (u32)__shfl_xor((int)X, 16, 64);
        oe = rowe ? X : t1;
        oo = rowe ? t2 : Y;
    };

    auto wavemax = [&](int v) {
        int s1 = __shfl_xor(v, 1, 64);  v = v > s1 ? v : s1;
        int s2 = __shfl_xor(v, 2, 64);  v = v > s2 ? v : s2;
        int s4 = __shfl_xor(v, 4, 64);  v = v > s4 ? v : s4;
        int s8 = __shfl_xor(v, 8, 64);  v = v > s8 ? v : s8;
        return v;
    };

    const int q0a = (7 - p) * 128, q0b = p * 128;

    const int qia = qidx[b * S_ + q0a + w * 16 + l15];
    const u16* qpa = qb + ((size_t)(b * S_ + qia)) * D_ + h * 64 + l4 * 8;
    const bf16x8 bqa0 = *(const bf16x8*)qpa;
    const bf16x8 bqa1 = *(const bf16x8*)(qpa + 32);
    const int vla = vlen[b * S_ + qia];

    const int qib = qidx[b * S_ + q0b + w * 16 + l15];
    const u16* qpb = qb + ((size_t)(b * S_ + qib)) * D_ + h * 64 + l4 * 8;
    const bf16x8 bqb0 = *(const bf16x8*)qpb;
    const bf16x8 bqb1 = *(const bf16x8*)(qpb + 32);
    const int vlb = vlen[b * S_ + qib];

    int mk = vlen[b * S_ + qidx[b * S_ + q0a + 127]];   // job A holds the block max (sorted)
    if (mk == 0) mk = S_;
    const int nkt = (mk + 63) >> 6;

    const int nktwa = (wavemax(vla == 0 ? S_ : vla) + 63) >> 6;
    const int nktwb = (wavemax(vlb == 0 ? S_ : vlb) + 63) >> 6;

    float ma = -3.0e38f, lsa = 0.f, mb = -3.0e38f, lsb = 0.f;
    f32x4 acca[4] = {}, accb[4] = {};   // acc[df][r] = out[q=l15][d = df*16 + 4*l4 + r]

    // per-tile compute for one job (inlined twice per tile)
    auto process = [&](int buf, int kt, const bf16x8& bq0, const bf16x8& bq1, int vlq,
                       float& m, float& lsum, f32x4 (&acc)[4]) {
        // --- QK^T swapped: S^T[k][q] ---
        f32x4 sc[4];
        __builtin_amdgcn_s_setprio(1);
        #pragma unroll
        for (int nf = 0; nf < 4; ++nf) {
            int kr = nf * 16 + l15, swz = kr & 7;
            bf16x8 ak0 = *(const bf16x8*)&kv(buf, 0)[kr * 64 + ((l4 ^ swz) * 8)];
            bf16x8 ak1 = *(const bf16x8*)&kv(buf, 0)[kr * 64 + (((l4 + 4) ^ swz) * 8)];
            f32x4 s = {0.f, 0.f, 0.f, 0.f};
            s = __builtin_amdgcn_mfma_f32_16x16x32_bf16(ak0, bq0, s, 0, 0, 0);
            s = __builtin_amdgcn_mfma_f32_16x16x32_bf16(ak1, bq1, s, 0, 0, 0);
            sc[nf] = s;
        }
        __builtin_amdgcn_s_setprio(0);

        // --- mask + online softmax (lane-local; q=l15-slot, k = kt*64 + nf*16 + 4*l4 + r) ---
        const int thr = vlq - kt * 64 - 4 * l4;
        float pv[16];
        float pm = -3.0e38f;
        if (__all(thr >= 52)) {
            #pragma unroll
            for (int nf = 0; nf < 4; ++nf)
                #pragma unroll
                for (int r = 0; r < 4; ++r) {
                    float y = sc[nf][r];
                    pv[nf * 4 + r] = y;
                    pm = fmaxf(pm, y);
                }
        } else {
            #pragma unroll
            for (int nf = 0; nf < 4; ++nf)
                #pragma unroll
                for (int r = 0; r < 4; ++r) {
                    float y = ((nf * 16 + r) < thr) ? sc[nf][r] : MASKVAL;
                    pv[nf * 4 + r] = y;
                    pm = fmaxf(pm, y);
                }
        }
        pm = fmaxf(pm, __shfl_xor(pm, 16, 64));
        pm = xor32max(pm);
        if (!__all(pm - m <= 8.0f)) {           // defer-max (T13)
            float mn = fmaxf(m, pm);
            float corr = __builtin_amdgcn_exp2f(m - mn);
            m = mn;
            lsum *= corr;
            #pragma unroll
            for (int df = 0; df < 4; ++df) acc[df] *= corr;
        }
        float rs = 0.f;
        #pragma unroll
        for (int i = 0; i < 16; ++i) {
            float e = __builtin_amdgcn_exp2f(pv[i] - m);
            pv[i] = e;
            rs += e;
        }
        rs += __shfl_xor(rs, 16, 64);
        rs = xor32add(rs);
        lsum += rs;

        // --- pack P -> bf16 pairs; redistribute to P^T B-fragments ---
        u32 pw[8];
        #pragma unroll
        for (int nf = 0; nf < 4; ++nf) {
            pw[2 * nf]     = cvtpk(pv[4 * nf + 0], pv[4 * nf + 1]);
            pw[2 * nf + 1] = cvtpk(pv[4 * nf + 2], pv[4 * nf + 3]);
        }
        U4 pb0, pb1;
        redist(pw[0], pw[2], pb0.u[0], pb0.u[2]);
        redist(pw[1], pw[3], pb0.u[1], pb0.u[3]);
        redist(pw[4], pw[6], pb1.u[0], pb1.u[2]);
        redist(pw[5], pw[7], pb1.u[1], pb1.u[3]);

        // --- PV swapped: out^T[d][q] += mfma(Vt_frag, P_frag) ---
        __builtin_amdgcn_s_setprio(1);
        #pragma unroll
        for (int df = 0; df < 4; ++df) {
            int vr = df * 16 + l15, swz = vr & 7;
            bf16x8 av0 = *(const bf16x8*)&kv(buf, 1)[vr * 64 + ((l4 ^ swz) * 8)];
            bf16x8 av1 = *(const bf16x8*)&kv(buf, 1)[vr * 64 + (((l4 + 4) ^ swz) * 8)];
            acc[df] = __builtin_amdgcn_mfma_f32_16x16x32_bf16(av0, pb0.v, acc[df], 0, 0, 0);
            acc[df] = __builtin_amdgcn_mfma_f32_16x16x32_bf16(av1, pb1.v, acc[df], 0, 0, 0);
        }
        __builtin_amdgcn_s_setprio(0);
    };

    stage(0, 0);
    __syncthreads();

    int buf = 0;
    for (int kt = 0; kt < nkt; ++kt) {
        if (kt + 1 < nkt) stage(buf ^ 1, kt + 1);
        if (kt < nktwa) process(buf, kt, bqa0, bqa1, vla, ma, lsa, acca);
        if (kt < nktwb) process(buf, kt, bqb0, bqb1, vlb, mb, lsb, accb);
        __syncthreads();
        buf ^= 1;
    }

    // --- epilogues: transpose acc through per-wave LDS region -> coalesced float4 stores ---
    // (no barriers: regions are per-wave-disjoint; intra-wave ds ordering via lgkmcnt)
    float* ep = (float*)smem_raw;          // per-wave region [16 q][68] f32 (8 waves = 34816 B)
    {
        const float inv = 1.0f / lsa;
        #pragma unroll
        for (int df = 0; df < 4; ++df)
            #pragma unroll
            for (int r = 0; r < 4; ++r)
                ep[w * 1088 + l15 * 68 + df * 16 + 4 * l4 + r] = acca[df][r] * inv;
        #pragma unroll
        for (int rr = 0; rr < 4; ++rr) {
            int row = l4 * 4 + rr;
            int qi2 = qidx[b * S_ + q0a + w * 16 + row];
            float4 vv = *(float4*)&ep[w * 1088 + row * 68 + l15 * 4];
            *(float4*)&out[((size_t)(b * S_ + qi2)) * D_ + h * 64 + l15 * 4] = vv;
        }
    }
    {
        const float inv = 1.0f / lsb;
        #pragma unroll
        for (int df = 0; df < 4; ++df)
            #pragma unroll
            for (int r = 0; r < 4; ++r)
                ep[w * 1088 + l15 * 68 + df * 16 + 4 * l4 + r] = accb[df][r] * inv;
        #pragma unroll
        for (int rr = 0; rr < 4; ++rr) {
            int row = l4 * 4 + rr;
            int qi2 = qidx[b * S_ + q0b + w * 16 + row];
            float4 vv = *(float4*)&ep[w * 1088 + row * 68 + l15 * 4];
            *(float4*)&out[((size_t)(b * S_ + qi2)) * D_ + h * 64 + l15 * 4] = vv;
        }
    }
}

extern "C" void kernel_launch(void* const* d_in, const int* in_sizes, int n_in,
                              void* d_out, int out_size, void* d_ws, size_t ws_size,
                              hipStream_t stream) {
    const float* query = (const float*)d_in[0];
    const float* key   = (const float*)d_in[1];
    const float* value = (const float*)d_in[2];
    const int*   vlen  = (const int*)d_in[3];
    const float* Wq    = (const float*)d_in[4];
    const float* Wk    = (const float*)d_in[5];
    const float* Wv    = (const float*)d_in[6];
    float* out = (float*)d_out;

    // workspace (~70 MB): wts 6 | vt 16 | qb kb | qidx 32KB
    char* ws = (char*)d_ws;
    const size_t MB = 1024 * 1024;
    const size_t TSZ = (size_t)B_ * S_ * D_ * 2;   // 16,777,216 B
    u16* wts = (u16*)(ws);                         // 3 x 1024x1024 bf16 (linear layout)
    u16* vt  = (u16*)(ws + 6 * MB);
    u16* qb  = (u16*)(ws + 6 * MB + TSZ);
    u16* kb  = (u16*)(ws + 6 * MB + 2 * TSZ);
    int* qidx = (int*)(ws + 6 * MB + 4 * TSZ);

    dim3 blk(256);

    transpose_w3_kernel<<<dim3(32, 32, 3), blk, 0, stream>>>(Wq, Wk, Wv, wts);
    sort_vlen_kernel<<<B_, dim3(1024), 0, stream>>>(vlen, qidx);

    gemm_qkv_kernel<<<dim3(64, 12), dim3(512), 0, stream>>>(query, key, value, wts, qb, kb, vt);

    attn_kernel<<<dim3(512), dim3(512), 0, stream>>>(qb, kb, vt, vlen, qidx, out);
}